// Round 15
// baseline (152.851 us; speedup 1.0000x reference)
//
#include <hip/hip_runtime.h>
#include <math.h>

#define D_MODEL 768
#define SEQ 2048
#define D_STATE 64
#define D_CONV 4
#define D_INNER 1536
#define HEADDIM 64
#define NHEADS 24
#define CONV_DIM 1664      // D_INNER + 2*D_STATE
#define D_IN_PROJ 3224     // 2*D_INNER + 2*D_STATE + NHEADS
#define HIDDEN 1536
#define EPS 1e-5f
#define NCHUNK 32
#define CHUNK 64

typedef short s16x8 __attribute__((ext_vector_type(8)));
typedef float f32x4 __attribute__((ext_vector_type(4)));
typedef float f32x16 __attribute__((ext_vector_type(16)));

// XOR-swizzled 64-short-stride bf16 tile: row stride 64 shorts (128B), 8-short
// slots, slot ^= (row&7). Involution; b128 reads spread rows -> low conflict.
#define SWZ(row, k) (((row) << 6) + ((((k) >> 3) ^ ((row) & 7)) << 3) + ((k) & 7))

// ---------------- helpers ---------------------------------------------------
__device__ __forceinline__ float silu_f(float x) { return x / (1.f + expf(-x)); }

__device__ __forceinline__ short f2bf(float x) {  // RNE fp32 -> bf16 bits
  unsigned u = __builtin_bit_cast(unsigned, x);
  unsigned r = (u + 0x7fffu + ((u >> 16) & 1u)) >> 16;
  return (short)r;
}
__device__ __forceinline__ float bf2f(short s) {
  unsigned u = ((unsigned)(unsigned short)s) << 16;
  return __builtin_bit_cast(float, u);
}

__device__ __forceinline__ float block_sum256(float v, float* sdata) {
#pragma unroll
  for (int o = 32; o > 0; o >>= 1) v += __shfl_down(v, o);
  int lane = threadIdx.x & 63, wid = threadIdx.x >> 6;
  __syncthreads();
  if (lane == 0) sdata[wid] = v;
  __syncthreads();
  if (threadIdx.x == 0) sdata[0] = sdata[0] + sdata[1] + sdata[2] + sdata[3];
  __syncthreads();
  return sdata[0];
}

// async 16B global->LDS (dest: wave-uniform base + lane*16)
__device__ __forceinline__ void gll16(const short* gsrc, const short* ldst) {
  __builtin_amdgcn_global_load_lds(
      (const __attribute__((address_space(1))) unsigned int*)(unsigned long long)gsrc,
      (__attribute__((address_space(3))) unsigned int*)(unsigned int)(unsigned long long)ldst,
      16, 0, 0);
}

// ------- LN row helper (over 768, writes bf16) -------------------------------
__device__ __forceinline__ void ln_row(const float* __restrict__ xr,
                                       const float* __restrict__ w,
                                       const float* __restrict__ b,
                                       short* __restrict__ orow, float* red) {
  float v[3];
#pragma unroll
  for (int k = 0; k < 3; k++) v[k] = xr[threadIdx.x + k * 256];
  float s = v[0] + v[1] + v[2];
  s = block_sum256(s, red);
  float mean = s * (1.f / 768.f);
  float q = 0.f;
#pragma unroll
  for (int k = 0; k < 3; k++) { float d = v[k] - mean; q += d * d; }
  q = block_sum256(q, red);
  float rstd = rsqrtf(q * (1.f / 768.f) + EPS);
#pragma unroll
  for (int k = 0; k < 3; k++) {
    int i = threadIdx.x + k * 256;
    orow[i] = f2bf((v[k] - mean) * rstd * w[i] + b[i]);
  }
}

__global__ __launch_bounds__(256) void ln_kernel(const float* __restrict__ x,
                                                 const float* __restrict__ w,
                                                 const float* __restrict__ b,
                                                 short* __restrict__ out) {
  __shared__ float red[8];
  int row = blockIdx.x;
  ln_row(x + (size_t)row * D_MODEL, w, b, out + (size_t)row * D_MODEL, red);
}

// ------- fused: LN1 (blocks 0..2047) | weight casts (rest) ------------------
// Wout cast has ssm_norm_w folded into its columns (RMSNorm factorization).
#define T_WINP (3328 * 768)
#define R_WINP (3224 * 768)
#define T_FC1 (3072 * 768)
#define T_W768 (1536 * 768)
__global__ __launch_bounds__(256) void cast_ln_kernel(
    const float* __restrict__ x, const float* __restrict__ ln1w,
    const float* __restrict__ ln1b, short* __restrict__ hbf,
    const float* __restrict__ Win, const float* __restrict__ Wfc1,
    const float* __restrict__ Wout, const float* __restrict__ Wfc2,
    const float* __restrict__ nrmw,
    short* __restrict__ WA, short* __restrict__ WF1,
    short* __restrict__ WB, short* __restrict__ WC) {
  __shared__ float red[8];
  if (blockIdx.x < SEQ) {
    int row = blockIdx.x;
    ln_row(x + (size_t)row * D_MODEL, ln1w, ln1b, hbf + (size_t)row * D_MODEL, red);
    return;
  }
  int idx = (blockIdx.x - SEQ) * 256 + threadIdx.x;
  if (idx < T_WINP) {
    WA[idx] = (idx < R_WINP) ? f2bf(Win[idx]) : (short)0;
    return;
  }
  idx -= T_WINP;
  if (idx < T_FC1) {  // interleave: dst row 2j=src j, 2j+1=src H+j
    int np = idx / 768, k = idx % 768;
    int srow = (np & 1) ? (HIDDEN + (np >> 1)) : (np >> 1);
    WF1[idx] = f2bf(Wfc1[(size_t)srow * 768 + k]);
    return;
  }
  idx -= T_FC1;
  if (idx < T_W768) {  // fold ssm_norm_w into Wout columns
    WB[idx] = f2bf(Wout[idx] * nrmw[idx % D_INNER]);
    return;
  }
  idx -= T_W768;
  if (idx < T_W768) WC[idx] = f2bf(Wfc2[idx]);
}

// ---------------- bf16 MFMA GEMM: C = A(MxK) * W(NpadxK)^T, BK=64 -----------
// 32x32x16 MFMA. WROWS x WCOLS waves; per-wave sub-tile (MT*32) x (NT*32);
// block tile = (WROWS*MT*32) x (WCOLS*NT*32). 1D grid, XCD-chunked swizzle:
// CHUNKMODE 0 = column-chunks (share A), 1 = row-chunks.
// OMODE: 0 = fp32 out (+res), 1 = bf16 out, 2 = bf16 GLU-pair out,
//        3 = fp32 out with per-row rs = rsqrt(mean(ssqp)+eps) scaling (+res)
template <int MT, int NT, int WROWS, int WCOLS, int CHUNKMODE, int OMODE>
__global__ __launch_bounds__(WROWS* WCOLS * 64) void mfma_gemm_bt(
    const short* __restrict__ A, const short* __restrict__ Bw,
    void* __restrict__ Cout, const float* __restrict__ res,
    const float* __restrict__ ssqp, int GX, int GY, int Nreal, int K) {
  constexpr int WAVES = WROWS * WCOLS;
  constexpr int BMr = WROWS * MT * 32;
  constexpr int BNr = WCOLS * NT * 32;
  __shared__ short As[BMr * 64];
  __shared__ short Bs[BNr * 64];
  __shared__ float rs_s[BMr];
  int tid = threadIdx.x, w = tid >> 6, l = tid & 63;
  // bijective XCD swizzle (gridDim.x % 8 == 0 for all call sites)
  int per8 = gridDim.x >> 3;
  int L = (blockIdx.x & 7) * per8 + (blockIdx.x >> 3);
  int xt, yt;
  if constexpr (CHUNKMODE == 0) { xt = L / GY; yt = L - xt * GY; }
  else                          { yt = L / GX; xt = L - yt * GX; }
  int m0 = yt * BMr, n0 = xt * BNr;
  int wr = (w / WCOLS) * (MT * 32), wc = (w % WCOLS) * (NT * 32);
  f32x16 acc[MT][NT] = {};

  if constexpr (OMODE == 3) {
    if (tid < BMr) {
      const float* sp = ssqp + (size_t)(m0 + tid) * NHEADS;
      float s = 0.f;
#pragma unroll
      for (int i = 0; i < NHEADS; i++) s += sp[i];
      rs_s[tid] = rsqrtf(s * (1.f / (float)D_INNER) + EPS);
    }
  }

  for (int kt = 0; kt < K; kt += 64) {
    __syncthreads();
    // stage A tile (BMr x 64 bf16): one gll16 issue = 8 rows x 128B
#pragma unroll
    for (int q = 0; q < BMr / 8 / WAVES; q++) {
      int chunk = w * (BMr / 8 / WAVES) + q;
      int rr = chunk * 8 + (l >> 3);
      int gs = (l & 7) ^ (rr & 7);
      gll16(A + (size_t)(m0 + rr) * K + kt + gs * 8, As + chunk * 512);
    }
#pragma unroll
    for (int q = 0; q < BNr / 8 / WAVES; q++) {
      int chunk = w * (BNr / 8 / WAVES) + q;
      int rr = chunk * 8 + (l >> 3);
      int gs = (l & 7) ^ (rr & 7);
      gll16(Bw + (size_t)(n0 + rr) * K + kt + gs * 8, Bs + chunk * 512);
    }
    __syncthreads();
    // 4 K-steps of 16; lane l holds k = (l>>5)*8 .. +7, row = l&31
#pragma unroll
    for (int step = 0; step < 4; step++) {
      s16x8 af[MT], bfr[NT];
      int kk = step * 16 + (l >> 5) * 8;
#pragma unroll
      for (int mi = 0; mi < MT; mi++)
        af[mi] = *(const s16x8*)&As[SWZ(wr + mi * 32 + (l & 31), kk)];
#pragma unroll
      for (int nj = 0; nj < NT; nj++)
        bfr[nj] = *(const s16x8*)&Bs[SWZ(wc + nj * 32 + (l & 31), kk)];
#pragma unroll
      for (int mi = 0; mi < MT; mi++)
#pragma unroll
        for (int nj = 0; nj < NT; nj++)
          acc[mi][nj] = __builtin_amdgcn_mfma_f32_32x32x16_bf16(af[mi], bfr[nj],
                                                                acc[mi][nj], 0, 0, 0);
    }
  }
  // epilogue: C/D map col=lane&31, row=(reg&3)+8*(reg>>2)+4*(lane>>5)
  // [m74/m101-verified]
#pragma unroll
  for (int mi = 0; mi < MT; mi++)
#pragma unroll
    for (int nj = 0; nj < NT; nj++)
#pragma unroll
      for (int r = 0; r < 16; r++) {
        int lr = wr + mi * 32 + (r & 3) + 8 * (r >> 2) + 4 * (l >> 5);
        int mm = m0 + lr;
        int nn = n0 + wc + nj * 32 + (l & 31);
        float v = acc[mi][nj][r];
        if constexpr (OMODE == 0) {
          float* C = (float*)Cout;
          if (nn < Nreal) {
            if (res) v += res[(size_t)mm * Nreal + nn];
            C[(size_t)mm * Nreal + nn] = v;
          }
        } else if constexpr (OMODE == 1) {
          short* C = (short*)Cout;
          if (nn < Nreal) C[(size_t)mm * Nreal + nn] = f2bf(v);
        } else if constexpr (OMODE == 2) {
          // GLU pair: even col = a, odd col = b (partner lane l^1); out = a*silu(b)
          float pv = __shfl_xor(v, 1);
          if ((l & 1) == 0) {
            short* g = (short*)Cout;
            g[(size_t)mm * (Nreal >> 1) + (nn >> 1)] = f2bf(v * silu_f(pv));
          }
        } else {
          float* C = (float*)Cout;
          if (nn < Nreal) {
            v = v * rs_s[lr] + res[(size_t)mm * Nreal + nn];
            C[(size_t)mm * Nreal + nn] = v;
          }
        }
      }
}

// ------- fused conv4+SiLU+pack (ct<26) and dt/softplus/la-cumsum (ct==26) ---
// ct<24: xs channels -> xsb only (transpose now done in ssd_a).
__global__ __launch_bounds__(256) void conv_pack_kernel(const short* __restrict__ zx,
                                                        const float* __restrict__ cw,
                                                        const float* __restrict__ cb,
                                                        const float* __restrict__ dtb,
                                                        const float* __restrict__ Alog,
                                                        short* __restrict__ xsb,
                                                        short* __restrict__ BTg,
                                                        short* __restrict__ BCbf,
                                                        float* __restrict__ dts,
                                                        float* __restrict__ laB) {
  int ct = blockIdx.x, rt = blockIdx.y;
  if (ct == 26) {  // dt path: chunk rt, 4 waves x 6 heads
    int wv = threadIdx.x >> 6, t = threadIdx.x & 63;
    int gt = rt * 64 + t;
#pragma unroll
    for (int i = 0; i < 6; i++) {
      int h = wv * 6 + i;
      float xv = bf2f(zx[(size_t)gt * D_IN_PROJ + 3200 + h]) + dtb[h];
      float sp = (xv > 20.f) ? xv : log1pf(expf(xv));
      float la = -expf(Alog[h]) * sp;
#pragma unroll
      for (int off = 1; off < 64; off <<= 1) {
        float u = __shfl_up(la, off);
        if (t >= off) la += u;
      }
      dts[gt * NHEADS + h] = sp;
      laB[gt * NHEADS + h] = la;
    }
    return;
  }
  __shared__ float T[64][65];
  int lane = threadIdx.x & 63, grp = threadIdx.x >> 6;
  int c = ct * 64 + lane;
  float4 w4 = *(const float4*)&cw[c * 4];
  float cbv = cb[c];
  int t0 = rt * 64 + grp * 16;
  float vbuf[19];
#pragma unroll
  for (int jj = 0; jj < 19; jj++) {
    int tt = t0 + jj - 3;
    vbuf[jj] = (tt >= 0) ? bf2f(zx[(size_t)tt * D_IN_PROJ + D_INNER + c]) : 0.f;
  }
#pragma unroll
  for (int j = 0; j < 16; j++) {
    float acc = cbv + vbuf[j] * w4.x + vbuf[j + 1] * w4.y +
                vbuf[j + 2] * w4.z + vbuf[j + 3] * w4.w;
    float v = silu_f(acc);
    int row = grp * 16 + j;
    if (ct < 24) {
      xsb[(size_t)(rt * 64 + row) * D_INNER + c] = f2bf(v);
    } else {
      T[row][lane] = v;
      BCbf[(size_t)(rt * 64 + row) * 128 + (ct - 24) * 64 + lane] = f2bf(v);
    }
  }
  if (ct == 24) {
    __syncthreads();
#pragma unroll
    for (int j = 0; j < 16; j++) {
      int cc = grp * 16 + j;
      BTg[(size_t)cc * 2048 + rt * 64 + lane] = f2bf(T[lane][cc]);
    }
  }
}

// ------- SSD-A per (chunk,head): G=C@B^T, M, y_diag=M@X, h_end=(wX)^T@B -----
// XT tile built by reg-staged transpose of xsb (row-major) into LDS.
__global__ __launch_bounds__(256) void ssd_a_kernel(const short* __restrict__ BCbf,
                                                    const short* __restrict__ xsb,
                                                    const short* __restrict__ BTg,
                                                    const float* __restrict__ laB,
                                                    const float* __restrict__ dts,
                                                    short* __restrict__ ylg,
                                                    short* __restrict__ Sbh) {
  __shared__ short Cl[4096], Bl[4096], XTl[4096], BTl[4096], Ml[4096];
  __shared__ float la_s[64], dt_s[64], w_s[64];
  int b = blockIdx.x;
  int c = b / NHEADS, h = b % NHEADS;
  int tid = threadIdx.x, w = tid >> 6, l = tid & 63;

  {
    const short* gC = BCbf + (size_t)(c * 64) * 128 + 64;
    const short* gB = BCbf + (size_t)(c * 64) * 128;
    const short* gT = BTg + c * 64;
#pragma unroll
    for (int q = 0; q < 2; q++) {
      int row = w * 16 + q * 8 + (l >> 3);
      int ks = (l & 7) ^ (row & 7);
      int lofs = (w * 16 + q * 8) * 64;
      gll16(gC + (size_t)row * 128 + ks * 8, Cl + lofs);
      gll16(gB + (size_t)row * 128 + ks * 8, Bl + lofs);
      gll16(gT + (size_t)row * 2048 + ks * 8, BTl + lofs);
    }
  }
  // reg-staged transpose: XTl[p][t] = xs[(c*64+t)][h*64+p]
  {
    const short* gX = xsb + (size_t)(c * 64) * D_INNER + h * 64;
    int t = tid >> 2, p0 = (tid & 3) * 16;
    s16x8 v0 = *(const s16x8*)(gX + (size_t)t * D_INNER + p0);
    s16x8 v1 = *(const s16x8*)(gX + (size_t)t * D_INNER + p0 + 8);
#pragma unroll
    for (int j = 0; j < 8; j++) {
      XTl[SWZ(p0 + j, t)] = v0[j];
      XTl[SWZ(p0 + 8 + j, t)] = v1[j];
    }
  }
  if (tid < 64) {
    la_s[tid] = laB[(c * CHUNK + tid) * NHEADS + h];
    dt_s[tid] = dts[(c * CHUNK + tid) * NHEADS + h];
  }
  __syncthreads();

  // G = C @ B^T
  f32x4 gacc[4] = {};
#pragma unroll
  for (int kt = 0; kt < 2; kt++) {
    int ar = w * 16 + (l & 15);
    int kk = kt * 32 + (l >> 4) * 8;
    s16x8 af = *(const s16x8*)&Cl[SWZ(ar, kk)];
#pragma unroll
    for (int nj = 0; nj < 4; nj++) {
      s16x8 bf_ = *(const s16x8*)&Bl[SWZ(nj * 16 + (l & 15), kk)];
      gacc[nj] = __builtin_amdgcn_mfma_f32_16x16x32_bf16(af, bf_, gacc[nj], 0, 0, 0);
    }
  }
  if (tid < 64) w_s[tid] = __expf(la_s[63] - la_s[tid]) * dt_s[tid];
  // M[t,s] = G * exp(la_t - la_s) * dt_s  (s<=t)
#pragma unroll
  for (int nj = 0; nj < 4; nj++)
#pragma unroll
    for (int r = 0; r < 4; r++) {
      int t = w * 16 + (l >> 4) * 4 + r;
      int s = nj * 16 + (l & 15);
      float m = (s <= t) ? gacc[nj][r] * __expf(la_s[t] - la_s[s]) * dt_s[s] : 0.f;
      Ml[SWZ(t, s)] = f2bf(m);
    }
  __syncthreads();
  // scale BTl[s][t] *= w[t]
  {
    int s = tid & 63, tg = (tid >> 6) * 16;
#pragma unroll
    for (int j = 0; j < 16; j++) {
      int t = tg + j;
      int a = SWZ(s, t);
      BTl[a] = f2bf(bf2f(BTl[a]) * w_s[t]);
    }
  }
  __syncthreads();

  // y_diag[t,p] = sum_s M[t,s] * XT[p,s]
  f32x4 yacc[4] = {};
#pragma unroll
  for (int kt = 0; kt < 2; kt++) {
    int ar = w * 16 + (l & 15);
    int kk = kt * 32 + (l >> 4) * 8;
    s16x8 af = *(const s16x8*)&Ml[SWZ(ar, kk)];
#pragma unroll
    for (int nj = 0; nj < 4; nj++) {
      s16x8 bf_ = *(const s16x8*)&XTl[SWZ(nj * 16 + (l & 15), kk)];
      yacc[nj] = __builtin_amdgcn_mfma_f32_16x16x32_bf16(af, bf_, yacc[nj], 0, 0, 0);
    }
  }
  // h_end[p,s] = sum_t XT[p,t]*w[t]*B[t,s]
  f32x4 hacc[4] = {};
#pragma unroll
  for (int kt = 0; kt < 2; kt++) {
    int ar = w * 16 + (l & 15);
    int kk = kt * 32 + (l >> 4) * 8;
    s16x8 af = *(const s16x8*)&XTl[SWZ(ar, kk)];
#pragma unroll
    for (int nj = 0; nj < 4; nj++) {
      s16x8 bf_ = *(const s16x8*)&BTl[SWZ(nj * 16 + (l & 15), kk)];
      hacc[nj] = __builtin_amdgcn_mfma_f32_16x16x32_bf16(af, bf_, hacc[nj], 0, 0, 0);
    }
  }
#pragma unroll
  for (int nj = 0; nj < 4; nj++)
#pragma unroll
    for (int r = 0; r < 4; r++) {
      int t = w * 16 + (l >> 4) * 4 + r;
      int p = nj * 16 + (l & 15);
      ylg[(size_t)(c * CHUNK + t) * D_INNER + h * 64 + p] = f2bf(yacc[nj][r]);
      Sbh[((size_t)(c * NHEADS + h) * 64 + t) * 64 + p] = f2bf(hacc[nj][r]);
    }
}

// ---- scan pass 2: chunk combine (bf16 in); emits h_start bf16 (Hsbf) -------
__global__ __launch_bounds__(256) void scan2_kernel(const short* __restrict__ Sbh,
                                                    const float* __restrict__ laB,
                                                    short* __restrict__ Hsbf) {
  int idx = blockIdx.x * 256 + threadIdx.x;  // [0, 24*4096)
  int hh = idx >> 12;
  int rem = idx & 4095;  // p*64 + s
  float Sv[NCHUNK];
#pragma unroll
  for (int c = 0; c < NCHUNK; c++)
    Sv[c] = bf2f(Sbh[((size_t)c * NHEADS + hh) * 4096 + rem]);
  float run = 0.f;
#pragma unroll
  for (int c = 0; c < NCHUNK; c++) {
    float P = __expf(laB[(c * CHUNK + CHUNK - 1) * NHEADS + hh]);
    Hsbf[((size_t)c * NHEADS + hh) * 4096 + rem] = f2bf(run);
    run = fmaf(P, run, Sv[c]);
  }
}

// --- SSD-B per (chunk,head): y += exp(la_t)*C@h_start^T + D*xs; gate;
//     emit per-(t,h) sum-of-squares partials for the fused RMSNorm -----------
__global__ __launch_bounds__(256) void ssd_b_kernel(const short* __restrict__ BCbf,
                                                    const short* __restrict__ Hsbf,
                                                    const float* __restrict__ laB,
                                                    const float* __restrict__ Dsk,
                                                    const short* __restrict__ xsb,
                                                    const short* __restrict__ zx,
                                                    short* __restrict__ ylg,
                                                    float* __restrict__ ssqp) {
  __shared__ short Cl[4096], Hl[4096];
  __shared__ float la_s[64];
  int b = blockIdx.x;
  int c = b / NHEADS, h = b % NHEADS;
  int tid = threadIdx.x, w = tid >> 6, l = tid & 63;
  {
    const short* gC = BCbf + (size_t)(c * 64) * 128 + 64;
    const short* gH = Hsbf + (size_t)(c * NHEADS + h) * 4096;
#pragma unroll
    for (int q = 0; q < 2; q++) {
      int row = w * 16 + q * 8 + (l >> 3);
      int ks = (l & 7) ^ (row & 7);
      int lofs = (w * 16 + q * 8) * 64;
      gll16(gC + (size_t)row * 128 + ks * 8, Cl + lofs);
      gll16(gH + (size_t)row * 64 + ks * 8, Hl + lofs);
    }
  }
  if (tid < 64) la_s[tid] = laB[(c * CHUNK + tid) * NHEADS + h];
  __syncthreads();
  f32x4 acc[4] = {};
#pragma unroll
  for (int kt = 0; kt < 2; kt++) {
    int ar = w * 16 + (l & 15);
    int kk = kt * 32 + (l >> 4) * 8;
    s16x8 af = *(const s16x8*)&Cl[SWZ(ar, kk)];
#pragma unroll
    for (int nj = 0; nj < 4; nj++) {
      s16x8 bf_ = *(const s16x8*)&Hl[SWZ(nj * 16 + (l & 15), kk)];
      acc[nj] = __builtin_amdgcn_mfma_f32_16x16x32_bf16(af, bf_, acc[nj], 0, 0, 0);
    }
  }
  float Dv = Dsk[h];
  float sq[4] = {0.f, 0.f, 0.f, 0.f};
#pragma unroll
  for (int nj = 0; nj < 4; nj++)
#pragma unroll
    for (int r = 0; r < 4; r++) {
      int t = w * 16 + (l >> 4) * 4 + r;
      int p = nj * 16 + (l & 15);
      size_t gt = c * CHUNK + t;
      size_t gi = gt * D_INNER + h * 64 + p;
      float yv = bf2f(ylg[gi]) + acc[nj][r] * __expf(la_s[t]) +
                 Dv * bf2f(xsb[gt * D_INNER + h * 64 + p]);
      float z = bf2f(zx[gt * D_IN_PROJ + h * 64 + p]);
      short gb = f2bf(yv * silu_f(z));
      ylg[gi] = gb;
      float gf = bf2f(gb);
      sq[r] += gf * gf;  // bf16-rounded g, matching what out_proj will read
    }
  // reduce sq over the 16 lanes sharing (w, l>>4); lane l&15==0 writes partial
#pragma unroll
  for (int r = 0; r < 4; r++) {
    float s = sq[r];
    s += __shfl_xor(s, 1); s += __shfl_xor(s, 2);
    s += __shfl_xor(s, 4); s += __shfl_xor(s, 8);
    if ((l & 15) == 0) {
      int t = w * 16 + (l >> 4) * 4 + r;
      ssqp[(size_t)(c * CHUNK + t) * NHEADS + h] = s;
    }
  }
}

// ----------------------------------------------------------------------------
extern "C" void kernel_launch(void* const* d_in, const int* in_sizes, int n_in,
                              void* d_out, int out_size, void* d_ws, size_t ws_size,
                              hipStream_t stream) {
  const float* x     = (const float*)d_in[0];
  const float* ln1w  = (const float*)d_in[1];
  const float* ln1b  = (const float*)d_in[2];
  const float* ln2w  = (const float*)d_in[3];
  const float* ln2b  = (const float*)d_in[4];
  const float* Win   = (const float*)d_in[5];
  const float* convw = (const float*)d_in[6];
  const float* convb = (const float*)d_in[7];
  const float* dtb   = (const float*)d_in[8];
  const float* Alog  = (const float*)d_in[9];
  const float* Dsk   = (const float*)d_in[10];
  const float* nrmw  = (const float*)d_in[11];
  const float* Wout  = (const float*)d_in[12];
  const float* Wfc1  = (const float*)d_in[13];
  const float* Wfc2  = (const float*)d_in[14];
  float* out = (float*)d_out;

  // ---- workspace layout (~58 MB) ----
  short* zxb   = (short*)d_ws;               // 6,602,752 sh (bf16 zx; reused: gbf)
  short* xsb   = zxb + 6602752;              // 3,145,728 sh
  short* ylg   = xsb + 3145728;              // 3,145,728 sh
  float* Sbf   = (float*)(ylg + 3145728);    // 3,145,728 f region (Sbh; then x1)
  float* dts   = Sbf + 3145728;              // 49,152 f (ssd in; then ssqp)
  float* laB   = dts + 49152;                // 49,152 f
  short* hbf   = (short*)(laB + 49152);      // 1,572,864 sh
  short* WA    = hbf + 1572864;              // 2,555,904 sh (Win pad)
  short* WF1   = WA + 2555904;               // 2,359,296 sh (fc1 interleaved)
  short* WB    = WF1 + 2359296;              // 1,179,648 sh (Wout * nw)
  short* WC    = WB + 1179648;               // 1,179,648 sh (Wfc2)
  short* Hsbf  = WC + 1179648;               // 3,145,728 sh (h_start states)
  short* BTg   = Hsbf + 3145728;             // 131,072 sh (B^T)
  short* BCbf  = BTg + 131072;               // 262,144 sh

  short* Sbh  = (short*)Sbf;                 // bf16 chunk states (6.3MB of region)
  float* x1   = Sbf;                         // overlay: Sbh dead after scan2
  float* ssqp = dts;                         // overlay: dts dead after ssd_a
  short* gbf  = zxb;                         // overlay: zx dead after ssd_b

  // 1) LN1 + all weight casts in one launch (nw folded into Wout)
  cast_ln_kernel<<<SEQ + (T_WINP + T_FC1 + 2 * T_W768 + 255) / 256, 256, 0, stream>>>(
      x, ln1w, ln1b, hbf, Win, Wfc1, Wout, Wfc2, nrmw, WA, WF1, WB, WC);
  // 2) in_proj: zx = h @ Win^T -> bf16 (128x256 tiles, 8 waves, col-chunk)
  mfma_gemm_bt<2, 2, 2, 4, 0, 1><<<13 * 16, 512, 0, stream>>>(
      hbf, WA, zxb, nullptr, nullptr, 13, 16, D_IN_PROJ, D_MODEL);
  // 3) fused conv+silu+pack + dt/la (ct==26)
  conv_pack_kernel<<<dim3(27, 32), 256, 0, stream>>>(zxb, convw, convb, dtb, Alog,
                                                     xsb, BTg, BCbf, dts, laB);
  // 4) SSD: diag + chunk states (in-kernel xs transpose), combine, off-diag
  ssd_a_kernel<<<NCHUNK * NHEADS, 256, 0, stream>>>(BCbf, xsb, BTg, laB, dts, ylg, Sbh);
  scan2_kernel<<<(NHEADS * 4096) / 256, 256, 0, stream>>>(Sbh, laB, Hsbf);
  ssd_b_kernel<<<NCHUNK * NHEADS, 256, 0, stream>>>(BCbf, Hsbf, laB, Dsk, xsb, zxb, ylg, ssqp);
  // 5) out_proj with fused RMSNorm + residual: x1 = x + rs*(g @ (Wout.nw)^T)
  mfma_gemm_bt<1, 1, 2, 2, 1, 3><<<12 * 32, 256, 0, stream>>>(
      ylg, WB, x1, x, ssqp, 12, 32, D_MODEL, D_INNER);
  // 6) LN2 -> bf16
  ln_kernel<<<SEQ, 256, 0, stream>>>(x1, ln2w, ln2b, hbf);
  // 7) fc1 (interleaved) + fused GLU -> bf16 (128x256 tiles, 8 waves)
  mfma_gemm_bt<2, 2, 2, 4, 0, 2><<<12 * 16, 512, 0, stream>>>(
      hbf, WF1, gbf, nullptr, nullptr, 12, 16, 2 * HIDDEN, D_MODEL);
  // 8) fc2 + residual: out = x1 + g @ Wfc2^T (row-chunk swizzle)
  mfma_gemm_bt<1, 1, 2, 2, 1, 0><<<12 * 32, 256, 0, stream>>>(
      gbf, WC, out, x1, nullptr, 12, 32, D_MODEL, HIDDEN);
}

// Round 16
// 143.507 us; speedup vs baseline: 1.0651x; 1.0651x over previous
//
#include <hip/hip_runtime.h>
#include <math.h>

#define D_MODEL 768
#define SEQ 2048
#define D_STATE 64
#define D_CONV 4
#define D_INNER 1536
#define HEADDIM 64
#define NHEADS 24
#define CONV_DIM 1664      // D_INNER + 2*D_STATE
#define D_IN_PROJ 3224     // 2*D_INNER + 2*D_STATE + NHEADS
#define HIDDEN 1536
#define EPS 1e-5f
#define NCHUNK 32
#define CHUNK 64

typedef short s16x8 __attribute__((ext_vector_type(8)));
typedef float f32x4 __attribute__((ext_vector_type(4)));
typedef float f32x16 __attribute__((ext_vector_type(16)));

// XOR-swizzled 64-short-stride bf16 tile: row stride 64 shorts (128B), 8-short
// slots, slot ^= (row&7). Involution; b128 reads spread rows -> low conflict.
#define SWZ(row, k) (((row) << 6) + ((((k) >> 3) ^ ((row) & 7)) << 3) + ((k) & 7))

// ---------------- helpers ---------------------------------------------------
__device__ __forceinline__ float silu_f(float x) { return x / (1.f + expf(-x)); }

__device__ __forceinline__ short f2bf(float x) {  // RNE fp32 -> bf16 bits
  unsigned u = __builtin_bit_cast(unsigned, x);
  unsigned r = (u + 0x7fffu + ((u >> 16) & 1u)) >> 16;
  return (short)r;
}
__device__ __forceinline__ float bf2f(short s) {
  unsigned u = ((unsigned)(unsigned short)s) << 16;
  return __builtin_bit_cast(float, u);
}

__device__ __forceinline__ float block_sum256(float v, float* sdata) {
#pragma unroll
  for (int o = 32; o > 0; o >>= 1) v += __shfl_down(v, o);
  int lane = threadIdx.x & 63, wid = threadIdx.x >> 6;
  __syncthreads();
  if (lane == 0) sdata[wid] = v;
  __syncthreads();
  if (threadIdx.x == 0) sdata[0] = sdata[0] + sdata[1] + sdata[2] + sdata[3];
  __syncthreads();
  return sdata[0];
}

// async 16B global->LDS (dest: wave-uniform base + lane*16)
__device__ __forceinline__ void gll16(const short* gsrc, const short* ldst) {
  __builtin_amdgcn_global_load_lds(
      (const __attribute__((address_space(1))) unsigned int*)(unsigned long long)gsrc,
      (__attribute__((address_space(3))) unsigned int*)(unsigned int)(unsigned long long)ldst,
      16, 0, 0);
}

// ------- LN row helper (over 768, writes bf16) -------------------------------
__device__ __forceinline__ void ln_row(const float* __restrict__ xr,
                                       const float* __restrict__ w,
                                       const float* __restrict__ b,
                                       short* __restrict__ orow, float* red) {
  float v[3];
#pragma unroll
  for (int k = 0; k < 3; k++) v[k] = xr[threadIdx.x + k * 256];
  float s = v[0] + v[1] + v[2];
  s = block_sum256(s, red);
  float mean = s * (1.f / 768.f);
  float q = 0.f;
#pragma unroll
  for (int k = 0; k < 3; k++) { float d = v[k] - mean; q += d * d; }
  q = block_sum256(q, red);
  float rstd = rsqrtf(q * (1.f / 768.f) + EPS);
#pragma unroll
  for (int k = 0; k < 3; k++) {
    int i = threadIdx.x + k * 256;
    orow[i] = f2bf((v[k] - mean) * rstd * w[i] + b[i]);
  }
}

__global__ __launch_bounds__(256) void ln_kernel(const float* __restrict__ x,
                                                 const float* __restrict__ w,
                                                 const float* __restrict__ b,
                                                 short* __restrict__ out) {
  __shared__ float red[8];
  int row = blockIdx.x;
  ln_row(x + (size_t)row * D_MODEL, w, b, out + (size_t)row * D_MODEL, red);
}

// ------- fused: LN1 (blocks 0..2047) | weight casts (rest) ------------------
// Wout cast has ssm_norm_w folded into its columns (RMSNorm factorization).
#define T_WINP (3328 * 768)
#define R_WINP (3224 * 768)
#define T_FC1 (3072 * 768)
#define T_W768 (1536 * 768)
__global__ __launch_bounds__(256) void cast_ln_kernel(
    const float* __restrict__ x, const float* __restrict__ ln1w,
    const float* __restrict__ ln1b, short* __restrict__ hbf,
    const float* __restrict__ Win, const float* __restrict__ Wfc1,
    const float* __restrict__ Wout, const float* __restrict__ Wfc2,
    const float* __restrict__ nrmw,
    short* __restrict__ WA, short* __restrict__ WF1,
    short* __restrict__ WB, short* __restrict__ WC) {
  __shared__ float red[8];
  if (blockIdx.x < SEQ) {
    int row = blockIdx.x;
    ln_row(x + (size_t)row * D_MODEL, ln1w, ln1b, hbf + (size_t)row * D_MODEL, red);
    return;
  }
  int idx = (blockIdx.x - SEQ) * 256 + threadIdx.x;
  if (idx < T_WINP) {
    WA[idx] = (idx < R_WINP) ? f2bf(Win[idx]) : (short)0;
    return;
  }
  idx -= T_WINP;
  if (idx < T_FC1) {  // interleave: dst row 2j=src j, 2j+1=src H+j
    int np = idx / 768, k = idx % 768;
    int srow = (np & 1) ? (HIDDEN + (np >> 1)) : (np >> 1);
    WF1[idx] = f2bf(Wfc1[(size_t)srow * 768 + k]);
    return;
  }
  idx -= T_FC1;
  if (idx < T_W768) {  // fold ssm_norm_w into Wout columns
    WB[idx] = f2bf(Wout[idx] * nrmw[idx % D_INNER]);
    return;
  }
  idx -= T_W768;
  if (idx < T_W768) WC[idx] = f2bf(Wfc2[idx]);
}

// ---------------- bf16 MFMA GEMM: C = A(MxK) * W(NpadxK)^T, BK=64 -----------
// 32x32x16 MFMA. WROWS x WCOLS waves; per-wave sub-tile (MT*32) x (NT*32);
// block tile = (WROWS*MT*32) x (WCOLS*NT*32). 1D grid, XCD-chunked swizzle:
// CHUNKMODE 0 = column-chunks (share A), 1 = row-chunks.
// OMODE: 0 = fp32 out (+res), 1 = bf16 out, 2 = bf16 GLU-pair out,
//        3 = fp32 out with per-row rs = rsqrt(mean(ssqp)+eps) scaling (+res)
template <int MT, int NT, int WROWS, int WCOLS, int CHUNKMODE, int OMODE>
__global__ __launch_bounds__(WROWS* WCOLS * 64) void mfma_gemm_bt(
    const short* __restrict__ A, const short* __restrict__ Bw,
    void* __restrict__ Cout, const float* __restrict__ res,
    const float* __restrict__ ssqp, int GX, int GY, int Nreal, int K) {
  constexpr int WAVES = WROWS * WCOLS;
  constexpr int BMr = WROWS * MT * 32;
  constexpr int BNr = WCOLS * NT * 32;
  __shared__ short As[BMr * 64];
  __shared__ short Bs[BNr * 64];
  __shared__ float rs_s[BMr];
  int tid = threadIdx.x, w = tid >> 6, l = tid & 63;
  // bijective XCD swizzle (gridDim.x % 8 == 0 for all call sites)
  int per8 = gridDim.x >> 3;
  int L = (blockIdx.x & 7) * per8 + (blockIdx.x >> 3);
  int xt, yt;
  if constexpr (CHUNKMODE == 0) { xt = L / GY; yt = L - xt * GY; }
  else                          { yt = L / GX; xt = L - yt * GX; }
  int m0 = yt * BMr, n0 = xt * BNr;
  int wr = (w / WCOLS) * (MT * 32), wc = (w % WCOLS) * (NT * 32);
  f32x16 acc[MT][NT] = {};

  if constexpr (OMODE == 3) {
    if (tid < BMr) {
      const float* sp = ssqp + (size_t)(m0 + tid) * NHEADS;
      float s = 0.f;
#pragma unroll
      for (int i = 0; i < NHEADS; i++) s += sp[i];
      rs_s[tid] = rsqrtf(s * (1.f / (float)D_INNER) + EPS);
    }
  }

  for (int kt = 0; kt < K; kt += 64) {
    __syncthreads();
    // stage A tile (BMr x 64 bf16): one gll16 issue = 8 rows x 128B
#pragma unroll
    for (int q = 0; q < BMr / 8 / WAVES; q++) {
      int chunk = w * (BMr / 8 / WAVES) + q;
      int rr = chunk * 8 + (l >> 3);
      int gs = (l & 7) ^ (rr & 7);
      gll16(A + (size_t)(m0 + rr) * K + kt + gs * 8, As + chunk * 512);
    }
#pragma unroll
    for (int q = 0; q < BNr / 8 / WAVES; q++) {
      int chunk = w * (BNr / 8 / WAVES) + q;
      int rr = chunk * 8 + (l >> 3);
      int gs = (l & 7) ^ (rr & 7);
      gll16(Bw + (size_t)(n0 + rr) * K + kt + gs * 8, Bs + chunk * 512);
    }
    __syncthreads();
    // 4 K-steps of 16; lane l holds k = (l>>5)*8 .. +7, row = l&31
#pragma unroll
    for (int step = 0; step < 4; step++) {
      s16x8 af[MT], bfr[NT];
      int kk = step * 16 + (l >> 5) * 8;
#pragma unroll
      for (int mi = 0; mi < MT; mi++)
        af[mi] = *(const s16x8*)&As[SWZ(wr + mi * 32 + (l & 31), kk)];
#pragma unroll
      for (int nj = 0; nj < NT; nj++)
        bfr[nj] = *(const s16x8*)&Bs[SWZ(wc + nj * 32 + (l & 31), kk)];
#pragma unroll
      for (int mi = 0; mi < MT; mi++)
#pragma unroll
        for (int nj = 0; nj < NT; nj++)
          acc[mi][nj] = __builtin_amdgcn_mfma_f32_32x32x16_bf16(af[mi], bfr[nj],
                                                                acc[mi][nj], 0, 0, 0);
    }
  }
  // epilogue: C/D map col=lane&31, row=(reg&3)+8*(reg>>2)+4*(lane>>5)
  // [m74/m101-verified]
#pragma unroll
  for (int mi = 0; mi < MT; mi++)
#pragma unroll
    for (int nj = 0; nj < NT; nj++)
#pragma unroll
      for (int r = 0; r < 16; r++) {
        int lr = wr + mi * 32 + (r & 3) + 8 * (r >> 2) + 4 * (l >> 5);
        int mm = m0 + lr;
        int nn = n0 + wc + nj * 32 + (l & 31);
        float v = acc[mi][nj][r];
        if constexpr (OMODE == 0) {
          float* C = (float*)Cout;
          if (nn < Nreal) {
            if (res) v += res[(size_t)mm * Nreal + nn];
            C[(size_t)mm * Nreal + nn] = v;
          }
        } else if constexpr (OMODE == 1) {
          short* C = (short*)Cout;
          if (nn < Nreal) C[(size_t)mm * Nreal + nn] = f2bf(v);
        } else if constexpr (OMODE == 2) {
          // GLU pair: even col = a, odd col = b (partner lane l^1); out = a*silu(b)
          float pv = __shfl_xor(v, 1);
          if ((l & 1) == 0) {
            short* g = (short*)Cout;
            g[(size_t)mm * (Nreal >> 1) + (nn >> 1)] = f2bf(v * silu_f(pv));
          }
        } else {
          float* C = (float*)Cout;
          if (nn < Nreal) {
            v = v * rs_s[lr] + res[(size_t)mm * Nreal + nn];
            C[(size_t)mm * Nreal + nn] = v;
          }
        }
      }
}

// ------- fused conv4+SiLU+pack (ct<26) and dt/softplus/la-cumsum (ct==26) ---
// ct<24: xs channels -> xsb only (transpose now done in ssd_a).
__global__ __launch_bounds__(256) void conv_pack_kernel(const short* __restrict__ zx,
                                                        const float* __restrict__ cw,
                                                        const float* __restrict__ cb,
                                                        const float* __restrict__ dtb,
                                                        const float* __restrict__ Alog,
                                                        short* __restrict__ xsb,
                                                        short* __restrict__ BTg,
                                                        short* __restrict__ BCbf,
                                                        float* __restrict__ dts,
                                                        float* __restrict__ laB) {
  int ct = blockIdx.x, rt = blockIdx.y;
  if (ct == 26) {  // dt path: chunk rt, 4 waves x 6 heads
    int wv = threadIdx.x >> 6, t = threadIdx.x & 63;
    int gt = rt * 64 + t;
#pragma unroll
    for (int i = 0; i < 6; i++) {
      int h = wv * 6 + i;
      float xv = bf2f(zx[(size_t)gt * D_IN_PROJ + 3200 + h]) + dtb[h];
      float sp = (xv > 20.f) ? xv : log1pf(expf(xv));
      float la = -expf(Alog[h]) * sp;
#pragma unroll
      for (int off = 1; off < 64; off <<= 1) {
        float u = __shfl_up(la, off);
        if (t >= off) la += u;
      }
      dts[gt * NHEADS + h] = sp;
      laB[gt * NHEADS + h] = la;
    }
    return;
  }
  __shared__ float T[64][65];
  int lane = threadIdx.x & 63, grp = threadIdx.x >> 6;
  int c = ct * 64 + lane;
  float4 w4 = *(const float4*)&cw[c * 4];
  float cbv = cb[c];
  int t0 = rt * 64 + grp * 16;
  float vbuf[19];
#pragma unroll
  for (int jj = 0; jj < 19; jj++) {
    int tt = t0 + jj - 3;
    vbuf[jj] = (tt >= 0) ? bf2f(zx[(size_t)tt * D_IN_PROJ + D_INNER + c]) : 0.f;
  }
#pragma unroll
  for (int j = 0; j < 16; j++) {
    float acc = cbv + vbuf[j] * w4.x + vbuf[j + 1] * w4.y +
                vbuf[j + 2] * w4.z + vbuf[j + 3] * w4.w;
    float v = silu_f(acc);
    int row = grp * 16 + j;
    if (ct < 24) {
      xsb[(size_t)(rt * 64 + row) * D_INNER + c] = f2bf(v);
    } else {
      T[row][lane] = v;
      BCbf[(size_t)(rt * 64 + row) * 128 + (ct - 24) * 64 + lane] = f2bf(v);
    }
  }
  if (ct == 24) {
    __syncthreads();
#pragma unroll
    for (int j = 0; j < 16; j++) {
      int cc = grp * 16 + j;
      BTg[(size_t)cc * 2048 + rt * 64 + lane] = f2bf(T[lane][cc]);
    }
  }
}

// ------- SSD-A per (chunk,head): G=C@B^T, M, y_diag=M@X, h_end=(wX)^T@B -----
// XT tile built by reg-staged transpose of xsb (row-major) into LDS.
__global__ __launch_bounds__(256) void ssd_a_kernel(const short* __restrict__ BCbf,
                                                    const short* __restrict__ xsb,
                                                    const short* __restrict__ BTg,
                                                    const float* __restrict__ laB,
                                                    const float* __restrict__ dts,
                                                    short* __restrict__ ylg,
                                                    short* __restrict__ Sbh) {
  __shared__ short Cl[4096], Bl[4096], XTl[4096], BTl[4096], Ml[4096];
  __shared__ float la_s[64], dt_s[64], w_s[64];
  int b = blockIdx.x;
  int c = b / NHEADS, h = b % NHEADS;
  int tid = threadIdx.x, w = tid >> 6, l = tid & 63;

  {
    const short* gC = BCbf + (size_t)(c * 64) * 128 + 64;
    const short* gB = BCbf + (size_t)(c * 64) * 128;
    const short* gT = BTg + c * 64;
#pragma unroll
    for (int q = 0; q < 2; q++) {
      int row = w * 16 + q * 8 + (l >> 3);
      int ks = (l & 7) ^ (row & 7);
      int lofs = (w * 16 + q * 8) * 64;
      gll16(gC + (size_t)row * 128 + ks * 8, Cl + lofs);
      gll16(gB + (size_t)row * 128 + ks * 8, Bl + lofs);
      gll16(gT + (size_t)row * 2048 + ks * 8, BTl + lofs);
    }
  }
  // reg-staged transpose: XTl[p][t] = xs[(c*64+t)][h*64+p]
  {
    const short* gX = xsb + (size_t)(c * 64) * D_INNER + h * 64;
    int t = tid >> 2, p0 = (tid & 3) * 16;
    s16x8 v0 = *(const s16x8*)(gX + (size_t)t * D_INNER + p0);
    s16x8 v1 = *(const s16x8*)(gX + (size_t)t * D_INNER + p0 + 8);
#pragma unroll
    for (int j = 0; j < 8; j++) {
      XTl[SWZ(p0 + j, t)] = v0[j];
      XTl[SWZ(p0 + 8 + j, t)] = v1[j];
    }
  }
  if (tid < 64) {
    la_s[tid] = laB[(c * CHUNK + tid) * NHEADS + h];
    dt_s[tid] = dts[(c * CHUNK + tid) * NHEADS + h];
  }
  __syncthreads();

  // G = C @ B^T
  f32x4 gacc[4] = {};
#pragma unroll
  for (int kt = 0; kt < 2; kt++) {
    int ar = w * 16 + (l & 15);
    int kk = kt * 32 + (l >> 4) * 8;
    s16x8 af = *(const s16x8*)&Cl[SWZ(ar, kk)];
#pragma unroll
    for (int nj = 0; nj < 4; nj++) {
      s16x8 bf_ = *(const s16x8*)&Bl[SWZ(nj * 16 + (l & 15), kk)];
      gacc[nj] = __builtin_amdgcn_mfma_f32_16x16x32_bf16(af, bf_, gacc[nj], 0, 0, 0);
    }
  }
  if (tid < 64) w_s[tid] = __expf(la_s[63] - la_s[tid]) * dt_s[tid];
  // M[t,s] = G * exp(la_t - la_s) * dt_s  (s<=t)
#pragma unroll
  for (int nj = 0; nj < 4; nj++)
#pragma unroll
    for (int r = 0; r < 4; r++) {
      int t = w * 16 + (l >> 4) * 4 + r;
      int s = nj * 16 + (l & 15);
      float m = (s <= t) ? gacc[nj][r] * __expf(la_s[t] - la_s[s]) * dt_s[s] : 0.f;
      Ml[SWZ(t, s)] = f2bf(m);
    }
  __syncthreads();
  // scale BTl[s][t] *= w[t]
  {
    int s = tid & 63, tg = (tid >> 6) * 16;
#pragma unroll
    for (int j = 0; j < 16; j++) {
      int t = tg + j;
      int a = SWZ(s, t);
      BTl[a] = f2bf(bf2f(BTl[a]) * w_s[t]);
    }
  }
  __syncthreads();

  // y_diag[t,p] = sum_s M[t,s] * XT[p,s]
  f32x4 yacc[4] = {};
#pragma unroll
  for (int kt = 0; kt < 2; kt++) {
    int ar = w * 16 + (l & 15);
    int kk = kt * 32 + (l >> 4) * 8;
    s16x8 af = *(const s16x8*)&Ml[SWZ(ar, kk)];
#pragma unroll
    for (int nj = 0; nj < 4; nj++) {
      s16x8 bf_ = *(const s16x8*)&XTl[SWZ(nj * 16 + (l & 15), kk)];
      yacc[nj] = __builtin_amdgcn_mfma_f32_16x16x32_bf16(af, bf_, yacc[nj], 0, 0, 0);
    }
  }
  // h_end[p,s] = sum_t XT[p,t]*w[t]*B[t,s]
  f32x4 hacc[4] = {};
#pragma unroll
  for (int kt = 0; kt < 2; kt++) {
    int ar = w * 16 + (l & 15);
    int kk = kt * 32 + (l >> 4) * 8;
    s16x8 af = *(const s16x8*)&XTl[SWZ(ar, kk)];
#pragma unroll
    for (int nj = 0; nj < 4; nj++) {
      s16x8 bf_ = *(const s16x8*)&BTl[SWZ(nj * 16 + (l & 15), kk)];
      hacc[nj] = __builtin_amdgcn_mfma_f32_16x16x32_bf16(af, bf_, hacc[nj], 0, 0, 0);
    }
  }
#pragma unroll
  for (int nj = 0; nj < 4; nj++)
#pragma unroll
    for (int r = 0; r < 4; r++) {
      int t = w * 16 + (l >> 4) * 4 + r;
      int p = nj * 16 + (l & 15);
      ylg[(size_t)(c * CHUNK + t) * D_INNER + h * 64 + p] = f2bf(yacc[nj][r]);
      Sbh[((size_t)(c * NHEADS + h) * 64 + t) * 64 + p] = f2bf(hacc[nj][r]);
    }
}

// ---- scan pass 2: chunk combine (bf16 in); emits h_start bf16 (Hsbf) -------
__global__ __launch_bounds__(256) void scan2_kernel(const short* __restrict__ Sbh,
                                                    const float* __restrict__ laB,
                                                    short* __restrict__ Hsbf) {
  int idx = blockIdx.x * 256 + threadIdx.x;  // [0, 24*4096)
  int hh = idx >> 12;
  int rem = idx & 4095;  // p*64 + s
  float Sv[NCHUNK];
#pragma unroll
  for (int c = 0; c < NCHUNK; c++)
    Sv[c] = bf2f(Sbh[((size_t)c * NHEADS + hh) * 4096 + rem]);
  float run = 0.f;
#pragma unroll
  for (int c = 0; c < NCHUNK; c++) {
    float P = __expf(laB[(c * CHUNK + CHUNK - 1) * NHEADS + hh]);
    Hsbf[((size_t)c * NHEADS + hh) * 4096 + rem] = f2bf(run);
    run = fmaf(P, run, Sv[c]);
  }
}

// --- SSD-B per (chunk,head): y += exp(la_t)*C@h_start^T + D*xs; gate;
//     emit per-(t,h) sum-of-squares partials for the fused RMSNorm -----------
__global__ __launch_bounds__(256) void ssd_b_kernel(const short* __restrict__ BCbf,
                                                    const short* __restrict__ Hsbf,
                                                    const float* __restrict__ laB,
                                                    const float* __restrict__ Dsk,
                                                    const short* __restrict__ xsb,
                                                    const short* __restrict__ zx,
                                                    short* __restrict__ ylg,
                                                    float* __restrict__ ssqp) {
  __shared__ short Cl[4096], Hl[4096];
  __shared__ float la_s[64];
  int b = blockIdx.x;
  int c = b / NHEADS, h = b % NHEADS;
  int tid = threadIdx.x, w = tid >> 6, l = tid & 63;
  {
    const short* gC = BCbf + (size_t)(c * 64) * 128 + 64;
    const short* gH = Hsbf + (size_t)(c * NHEADS + h) * 4096;
#pragma unroll
    for (int q = 0; q < 2; q++) {
      int row = w * 16 + q * 8 + (l >> 3);
      int ks = (l & 7) ^ (row & 7);
      int lofs = (w * 16 + q * 8) * 64;
      gll16(gC + (size_t)row * 128 + ks * 8, Cl + lofs);
      gll16(gH + (size_t)row * 64 + ks * 8, Hl + lofs);
    }
  }
  if (tid < 64) la_s[tid] = laB[(c * CHUNK + tid) * NHEADS + h];
  __syncthreads();
  f32x4 acc[4] = {};
#pragma unroll
  for (int kt = 0; kt < 2; kt++) {
    int ar = w * 16 + (l & 15);
    int kk = kt * 32 + (l >> 4) * 8;
    s16x8 af = *(const s16x8*)&Cl[SWZ(ar, kk)];
#pragma unroll
    for (int nj = 0; nj < 4; nj++) {
      s16x8 bf_ = *(const s16x8*)&Hl[SWZ(nj * 16 + (l & 15), kk)];
      acc[nj] = __builtin_amdgcn_mfma_f32_16x16x32_bf16(af, bf_, acc[nj], 0, 0, 0);
    }
  }
  float Dv = Dsk[h];
  float sq[4] = {0.f, 0.f, 0.f, 0.f};
#pragma unroll
  for (int nj = 0; nj < 4; nj++)
#pragma unroll
    for (int r = 0; r < 4; r++) {
      int t = w * 16 + (l >> 4) * 4 + r;
      int p = nj * 16 + (l & 15);
      size_t gt = c * CHUNK + t;
      size_t gi = gt * D_INNER + h * 64 + p;
      float yv = bf2f(ylg[gi]) + acc[nj][r] * __expf(la_s[t]) +
                 Dv * bf2f(xsb[gt * D_INNER + h * 64 + p]);
      float z = bf2f(zx[gt * D_IN_PROJ + h * 64 + p]);
      short gb = f2bf(yv * silu_f(z));
      ylg[gi] = gb;
      float gf = bf2f(gb);
      sq[r] += gf * gf;  // bf16-rounded g, matching what out_proj will read
    }
  // reduce sq over the 16 lanes sharing (w, l>>4); lane l&15==0 writes partial
#pragma unroll
  for (int r = 0; r < 4; r++) {
    float s = sq[r];
    s += __shfl_xor(s, 1); s += __shfl_xor(s, 2);
    s += __shfl_xor(s, 4); s += __shfl_xor(s, 8);
    if ((l & 15) == 0) {
      int t = w * 16 + (l >> 4) * 4 + r;
      ssqp[(size_t)(c * CHUNK + t) * NHEADS + h] = s;
    }
  }
}

// ----------------------------------------------------------------------------
extern "C" void kernel_launch(void* const* d_in, const int* in_sizes, int n_in,
                              void* d_out, int out_size, void* d_ws, size_t ws_size,
                              hipStream_t stream) {
  const float* x     = (const float*)d_in[0];
  const float* ln1w  = (const float*)d_in[1];
  const float* ln1b  = (const float*)d_in[2];
  const float* ln2w  = (const float*)d_in[3];
  const float* ln2b  = (const float*)d_in[4];
  const float* Win   = (const float*)d_in[5];
  const float* convw = (const float*)d_in[6];
  const float* convb = (const float*)d_in[7];
  const float* dtb   = (const float*)d_in[8];
  const float* Alog  = (const float*)d_in[9];
  const float* Dsk   = (const float*)d_in[10];
  const float* nrmw  = (const float*)d_in[11];
  const float* Wout  = (const float*)d_in[12];
  const float* Wfc1  = (const float*)d_in[13];
  const float* Wfc2  = (const float*)d_in[14];
  float* out = (float*)d_out;

  // ---- workspace layout (~58 MB) ----
  short* zxb   = (short*)d_ws;               // 6,602,752 sh (bf16 zx; reused: gbf)
  short* xsb   = zxb + 6602752;              // 3,145,728 sh
  short* ylg   = xsb + 3145728;              // 3,145,728 sh
  float* Sbf   = (float*)(ylg + 3145728);    // 3,145,728 f region (Sbh; then x1)
  float* dts   = Sbf + 3145728;              // 49,152 f (ssd in; then ssqp)
  float* laB   = dts + 49152;                // 49,152 f
  short* hbf   = (short*)(laB + 49152);      // 1,572,864 sh
  short* WA    = hbf + 1572864;              // 2,555,904 sh (Win pad)
  short* WF1   = WA + 2555904;               // 2,359,296 sh (fc1 interleaved)
  short* WB    = WF1 + 2359296;              // 1,179,648 sh (Wout * nw)
  short* WC    = WB + 1179648;               // 1,179,648 sh (Wfc2)
  short* Hsbf  = WC + 1179648;               // 3,145,728 sh (h_start states)
  short* BTg   = Hsbf + 3145728;             // 131,072 sh (B^T)
  short* BCbf  = BTg + 131072;               // 262,144 sh

  short* Sbh  = (short*)Sbf;                 // bf16 chunk states (6.3MB of region)
  float* x1   = Sbf;                         // overlay: Sbh dead after scan2
  float* ssqp = dts;                         // overlay: dts dead after ssd_a
  short* gbf  = zxb;                         // overlay: zx dead after ssd_b

  // 1) LN1 + all weight casts in one launch (nw folded into Wout)
  cast_ln_kernel<<<SEQ + (T_WINP + T_FC1 + 2 * T_W768 + 255) / 256, 256, 0, stream>>>(
      x, ln1w, ln1b, hbf, Win, Wfc1, Wout, Wfc2, nrmw, WA, WF1, WB, WC);
  // 2) in_proj: zx = h @ Win^T -> bf16 (128x128 tiles, 8 waves, col-chunk)
  mfma_gemm_bt<2, 1, 2, 4, 0, 1><<<26 * 16, 512, 0, stream>>>(
      hbf, WA, zxb, nullptr, nullptr, 26, 16, D_IN_PROJ, D_MODEL);
  // 3) fused conv+silu+pack + dt/la (ct==26)
  conv_pack_kernel<<<dim3(27, 32), 256, 0, stream>>>(zxb, convw, convb, dtb, Alog,
                                                     xsb, BTg, BCbf, dts, laB);
  // 4) SSD: diag + chunk states (in-kernel xs transpose), combine, off-diag
  ssd_a_kernel<<<NCHUNK * NHEADS, 256, 0, stream>>>(BCbf, xsb, BTg, laB, dts, ylg, Sbh);
  scan2_kernel<<<(NHEADS * 4096) / 256, 256, 0, stream>>>(Sbh, laB, Hsbf);
  ssd_b_kernel<<<NCHUNK * NHEADS, 256, 0, stream>>>(BCbf, Hsbf, laB, Dsk, xsb, zxb, ylg, ssqp);
  // 5) out_proj with fused RMSNorm + residual: x1 = x + rs*(g @ (Wout.nw)^T)
  mfma_gemm_bt<1, 1, 2, 2, 1, 3><<<12 * 32, 256, 0, stream>>>(
      ylg, WB, x1, x, ssqp, 12, 32, D_MODEL, D_INNER);
  // 6) LN2 -> bf16
  ln_kernel<<<SEQ, 256, 0, stream>>>(x1, ln2w, ln2b, hbf);
  // 7) fc1 (interleaved) + fused GLU -> bf16 (128x128 tiles, 8 waves)
  mfma_gemm_bt<2, 1, 2, 4, 0, 2><<<24 * 16, 512, 0, stream>>>(
      hbf, WF1, gbf, nullptr, nullptr, 24, 16, 2 * HIDDEN, D_MODEL);
  // 8) fc2 + residual: out = x1 + g @ Wfc2^T (row-chunk swizzle)
  mfma_gemm_bt<1, 1, 2, 2, 1, 0><<<12 * 32, 256, 0, stream>>>(
      gbf, WC, out, x1, nullptr, 12, 32, D_MODEL, HIDDEN);
}